// Round 1
// baseline (99.870 us; speedup 1.0000x reference)
//
#include <hip/hip_runtime.h>
#include <math.h>

// Problem constants
#define BB 128
#define MM 50
#define CC 43
#define IMGF 416.0f

// Per-scale geometry:
//  s=0: W=52 A=2704 stride=8  chunks/b=11  blocks [0,1408)
//  s=1: W=26 A=676  stride=16 chunks/b=3   blocks [1408,1792)
//  s=2: W=13 A=169  stride=32 chunks/b=1   blocks [1792,1920)
#define NBLK0 1408
#define NBLK01 1792
#define NBLK_TOTAL 1920

__device__ __forceinline__ float bce_logits(float x, float t) {
    return fmaxf(x, 0.0f) - x * t + log1pf(expf(-fabsf(x)));
}

__device__ __forceinline__ float focal(float x, float t) {
    float b = bce_logits(x, t);
    float pt = expf(-b);
    float om = 1.0f - pt;
    return 0.25f * om * om * b;
}

__global__ __launch_bounds__(256) void v3_main(
    const float* __restrict__ cls0, const float* __restrict__ reg0, const float* __restrict__ obj0,
    const float* __restrict__ cls1, const float* __restrict__ reg1, const float* __restrict__ obj1,
    const float* __restrict__ cls2, const float* __restrict__ reg2, const float* __restrict__ obj2,
    const float* __restrict__ bboxes, const int* __restrict__ labels,
    float* __restrict__ partials)
{
    int bid = blockIdx.x;
    int s, b, chunk;
    if (bid < NBLK0)       { s = 0; b = bid / 11; chunk = bid - 11 * b; }
    else if (bid < NBLK01) { int r = bid - NBLK0; s = 1; b = r / 3; chunk = r - 3 * b; }
    else                   { s = 2; b = bid - NBLK01; chunk = 0; }

    const int   W      = (s == 0) ? 52 : ((s == 1) ? 26 : 13);
    const int   A      = W * W;
    const float stride = (s == 0) ? 8.0f : ((s == 1) ? 16.0f : 32.0f);
    const float* __restrict__ cls = (s == 0) ? cls0 : ((s == 1) ? cls1 : cls2);
    const float* __restrict__ reg = (s == 0) ? reg0 : ((s == 1) ? reg1 : reg2);
    const float* __restrict__ obj = (s == 0) ? obj0 : ((s == 1) ? obj1 : obj2);

    // Stage GTs for this image in LDS.
    __shared__ float s_bx1[MM], s_by1[MM], s_bx2[MM], s_by2[MM];
    __shared__ int s_gx[MM], s_gy[MM];
    __shared__ unsigned s_mlo[MM], s_mhi[MM];

    const int tid = threadIdx.x;
    if (tid < MM) {
        const float* bb = bboxes + ((size_t)b * MM + tid) * 4;
        float x1 = bb[0] * IMGF, y1 = bb[1] * IMGF, x2 = bb[2] * IMGF, y2 = bb[3] * IMGF;
        int lab = labels[b * MM + tid];
        s_bx1[tid] = x1; s_by1[tid] = y1; s_bx2[tid] = x2; s_by2[tid] = y2;
        int gx, gy;
        if (lab >= 0) {
            float cx = (x1 + x2) * 0.5f;
            float cy = (y1 + y2) * 0.5f;
            gx = (int)(cx / stride); gx = min(max(gx, 0), W - 1);
            gy = (int)(cy / stride); gy = min(max(gy, 0), W - 1);
        } else {
            gx = -100000; gy = -100000;   // never matches
        }
        s_gx[tid] = gx; s_gy[tid] = gy;
        int labc = min(max(lab, 0), CC - 1);
        s_mlo[tid] = (labc < 32) ? (1u << labc) : 0u;
        s_mhi[tid] = (labc >= 32) ? (1u << (labc - 32)) : 0u;
    }
    __syncthreads();

    const int a = chunk * 256 + tid;
    const bool active = (a < A);
    const int ay = a / W;
    const int ax = a - ay * W;

    // Scan the 50 GTs: fg flag, multi-hot class bits (OR), last-match box.
    bool fg = false;
    unsigned lo = 0, hi = 0;
    float t0 = 0.f, t1 = 0.f, t2 = 0.f, t3 = 0.f;
    for (int m = 0; m < MM; ++m) {
        int dx = ax - s_gx[m] + 1;
        int dy = ay - s_gy[m] + 1;
        bool match = ((unsigned)dx <= 2u) & ((unsigned)dy <= 2u);
        if (match) {
            fg = true;
            lo |= s_mlo[m];
            hi |= s_mhi[m];
            t0 = s_bx1[m]; t1 = s_by1[m]; t2 = s_bx2[m]; t3 = s_by2[m];
        }
    }

    float obj_t = 0.f, cls_t = 0.f, box_t = 0.f, nfg = 0.f;
    if (active) {
        // objectness BCE over ALL anchors
        float xo = obj[(size_t)b * A + a];
        obj_t = bce_logits(xo, fg ? 1.0f : 0.0f);

        if (fg) {
            nfg = 1.0f;
            // ---- box loss: decode + IoU with target ----
            const float* rp = reg + (size_t)b * 4 * A + a;
            float rx = rp[0], ry = rp[(size_t)A], rw = rp[(size_t)2 * A], rh = rp[(size_t)3 * A];
            float px = ((float)ax + rx) * stride;
            float py = ((float)ay + ry) * stride;
            rw = fminf(fmaxf(rw, -10.0f), 10.0f);
            rh = fminf(fmaxf(rh, -10.0f), 10.0f);
            float pw = expf(rw) * stride;
            float ph = expf(rh) * stride;
            float p0 = px - pw * 0.5f, p1 = py - ph * 0.5f;
            float p2 = px + pw * 0.5f, p3 = py + ph * 0.5f;
            float ix1 = fmaxf(p0, t0), iy1 = fmaxf(p1, t1);
            float ix2 = fminf(p2, t2), iy2 = fminf(p3, t3);
            float inter = fmaxf(ix2 - ix1, 0.0f) * fmaxf(iy2 - iy1, 0.0f);
            float pa = (p2 - p0) * (p3 - p1);
            float ta = (t2 - t0) * (t3 - t1);
            float iou = inter / (pa + ta - inter + 1e-7f);
            box_t = 1.0f - iou;

            // ---- cls focal loss over all 43 channels (multi-hot target) ----
            const float* cp = cls + (size_t)b * CC * A + a;
            float acc = 0.0f;
            for (int c = 0; c < CC; ++c) {
                float xv = cp[(size_t)c * A];
                unsigned bit = (c < 32) ? ((lo >> c) & 1u) : ((hi >> (c - 32)) & 1u);
                acc += focal(xv, (float)bit);
            }
            cls_t = acc;
        }
    }

    // Deterministic block reduction: wave shfl_xor then LDS across 4 waves.
    for (int off = 32; off > 0; off >>= 1) {
        obj_t += __shfl_xor(obj_t, off);
        cls_t += __shfl_xor(cls_t, off);
        box_t += __shfl_xor(box_t, off);
        nfg   += __shfl_xor(nfg,   off);
    }
    __shared__ float s_red[4][4];
    int wid = tid >> 6, lane = tid & 63;
    if (lane == 0) {
        s_red[wid][0] = obj_t; s_red[wid][1] = cls_t;
        s_red[wid][2] = box_t; s_red[wid][3] = nfg;
    }
    __syncthreads();
    if (tid == 0) {
        float o = 0.f, c = 0.f, bx = 0.f, nf = 0.f;
        for (int w = 0; w < 4; ++w) {
            o += s_red[w][0]; c += s_red[w][1]; bx += s_red[w][2]; nf += s_red[w][3];
        }
        float* p = partials + (size_t)bid * 4;
        p[0] = o; p[1] = c; p[2] = bx; p[3] = nf;
    }
}

__global__ __launch_bounds__(256) void v3_final(const float* __restrict__ partials,
                                                float* __restrict__ out)
{
    const int tid = threadIdx.x;
    double o[3] = {0, 0, 0}, c[3] = {0, 0, 0}, bx[3] = {0, 0, 0}, nf[3] = {0, 0, 0};
    for (int i = tid; i < NBLK_TOTAL; i += 256) {
        int s = (i < NBLK0) ? 0 : ((i < NBLK01) ? 1 : 2);
        const float* p = partials + (size_t)i * 4;
        o[s]  += (double)p[0];
        c[s]  += (double)p[1];
        bx[s] += (double)p[2];
        nf[s] += (double)p[3];
    }
    for (int off = 32; off > 0; off >>= 1) {
        for (int s = 0; s < 3; ++s) {
            o[s]  += __shfl_xor(o[s],  off);
            c[s]  += __shfl_xor(c[s],  off);
            bx[s] += __shfl_xor(bx[s], off);
            nf[s] += __shfl_xor(nf[s], off);
        }
    }
    __shared__ double s_red[4][12];
    int wid = tid >> 6, lane = tid & 63;
    if (lane == 0) {
        for (int s = 0; s < 3; ++s) {
            s_red[wid][s * 4 + 0] = o[s];
            s_red[wid][s * 4 + 1] = c[s];
            s_red[wid][s * 4 + 2] = bx[s];
            s_red[wid][s * 4 + 3] = nf[s];
        }
    }
    __syncthreads();
    if (tid == 0) {
        double total = 0.0;
        for (int s = 0; s < 3; ++s) {
            double os = 0, cs = 0, bs = 0, ns = 0;
            for (int w = 0; w < 4; ++w) {
                os += s_red[w][s * 4 + 0];
                cs += s_red[w][s * 4 + 1];
                bs += s_red[w][s * 4 + 2];
                ns += s_red[w][s * 4 + 3];
            }
            double n = (ns > 1.0) ? ns : 1.0;
            total += 0.5 * (cs / (n * (double)CC)) + 7.5 * (bs / n) + 1.0 * (os / n);
        }
        out[0] = (float)(total / 3.0);
    }
}

extern "C" void kernel_launch(void* const* d_in, const int* in_sizes, int n_in,
                              void* d_out, int out_size, void* d_ws, size_t ws_size,
                              hipStream_t stream) {
    const float* cls0 = (const float*)d_in[0];
    const float* reg0 = (const float*)d_in[1];
    const float* obj0 = (const float*)d_in[2];
    const float* cls1 = (const float*)d_in[3];
    const float* reg1 = (const float*)d_in[4];
    const float* obj1 = (const float*)d_in[5];
    const float* cls2 = (const float*)d_in[6];
    const float* reg2 = (const float*)d_in[7];
    const float* obj2 = (const float*)d_in[8];
    const float* bboxes = (const float*)d_in[9];
    const int*   labels = (const int*)d_in[10];

    float* partials = (float*)d_ws;   // 1920*4 floats = 30720 B

    v3_main<<<NBLK_TOTAL, 256, 0, stream>>>(cls0, reg0, obj0, cls1, reg1, obj1,
                                            cls2, reg2, obj2, bboxes, labels, partials);
    v3_final<<<1, 256, 0, stream>>>(partials, (float*)d_out);
}

// Round 2
// 49.113 us; speedup vs baseline: 2.0335x; 2.0335x over previous
//
#include <hip/hip_runtime.h>
#include <math.h>

// Problem constants
#define BB 128
#define MM 50
#define CC 43
#define IMGF 416.0f

// Per-scale geometry:
//  s=0: W=52 A=2704 stride=8  chunks/b=11  blocks [0,1408)
//  s=1: W=26 A=676  stride=16 chunks/b=3   blocks [1408,1792)
//  s=2: W=13 A=169  stride=32 chunks/b=1   blocks [1792,1920)
#define NBLK0 1408
#define NBLK01 1792
#define NBLK_TOTAL 1920

#define CELLS_PER_IMG 3549   // 2704 + 676 + 169
#define SOFF1 2704
#define SOFF2 3380
#define NCELLS (BB * CELLS_PER_IMG)   // 454272

// fast, algebraically-equivalent focal:
// bce = max(x,0) - x*t + log1p(e^-|x|);  pt = exp(-bce) == (t ? sig(x) : 1-sig(x))
__device__ __forceinline__ float focal_fast(float x, bool t) {
    float e = __expf(-fabsf(x));          // v_exp
    float denom = 1.0f + e;
    float l = __logf(denom);              // v_log : log(1+e) == log1p(e^-|x|)
    float bce = fmaxf(x, 0.0f) - (t ? x : 0.0f) + l;
    float r = __builtin_amdgcn_rcpf(denom);   // v_rcp
    float sig = (x >= 0.0f) ? r : e * r;
    float pt = t ? sig : 1.0f - sig;
    float om = 1.0f - pt;
    return 0.25f * om * om * bce;
}

__device__ __forceinline__ float bce_fast(float x, bool t) {
    float e = __expf(-fabsf(x));
    float l = __logf(1.0f + e);
    return fmaxf(x, 0.0f) - (t ? x : 0.0f) + l;
}

// K1: per-image GT scatter. Block b owns image b's cells exclusively, so it
// inits them then scatters its own GTs with LDS-free global atomics.
__global__ __launch_bounds__(256) void v3_assign(
    const float* __restrict__ bboxes, const int* __restrict__ labels,
    int* __restrict__ lastGT, unsigned* __restrict__ mlo, unsigned* __restrict__ mhi)
{
    const int b = blockIdx.x;
    const int tid = threadIdx.x;
    const size_t base = (size_t)b * CELLS_PER_IMG;
    for (int i = tid; i < CELLS_PER_IMG; i += 256) {
        lastGT[base + i] = -1;
        mlo[base + i] = 0u;
        mhi[base + i] = 0u;
    }
    __syncthreads();
    if (tid < 150) {
        int s = tid / 50, m = tid - s * 50;
        int lab = labels[b * MM + m];
        if (lab >= 0) {
            const float* bb = bboxes + ((size_t)b * MM + m) * 4;
            float cx = (bb[0] + bb[2]) * 0.5f * IMGF;
            float cy = (bb[1] + bb[3]) * 0.5f * IMGF;
            const int W = (s == 0) ? 52 : ((s == 1) ? 26 : 13);
            const float stride = (s == 0) ? 8.0f : ((s == 1) ? 16.0f : 32.0f);
            const int soff = (s == 0) ? 0 : ((s == 1) ? SOFF1 : SOFF2);
            int gx = (int)(cx / stride); gx = min(max(gx, 0), W - 1);
            int gy = (int)(cy / stride); gy = min(max(gy, 0), W - 1);
            int labc = min(max(lab, 0), CC - 1);
            unsigned lo = (labc < 32) ? (1u << labc) : 0u;
            unsigned hi = (labc >= 32) ? (1u << (labc - 32)) : 0u;
            for (int dy = -1; dy <= 1; ++dy) {
                for (int dx = -1; dx <= 1; ++dx) {
                    int axc = gx + dx, ayc = gy + dy;
                    if (axc >= 0 && axc < W && ayc >= 0 && ayc < W) {
                        size_t idx = base + soff + (size_t)(ayc * W + axc);
                        atomicMax(&lastGT[idx], m);     // last-write-wins == max GT idx
                        if (lo) atomicOr(&mlo[idx], lo);
                        if (hi) atomicOr(&mhi[idx], hi);
                    }
                }
            }
        }
    }
}

// K2: per-anchor loss. Reads its own cell's assignment (coalesced), no GT scan.
__global__ __launch_bounds__(256) void v3_main(
    const float* __restrict__ cls0, const float* __restrict__ reg0, const float* __restrict__ obj0,
    const float* __restrict__ cls1, const float* __restrict__ reg1, const float* __restrict__ obj1,
    const float* __restrict__ cls2, const float* __restrict__ reg2, const float* __restrict__ obj2,
    const float* __restrict__ bboxes,
    const int* __restrict__ lastGT, const unsigned* __restrict__ mlo, const unsigned* __restrict__ mhi,
    float* __restrict__ partials)
{
    int bid = blockIdx.x;
    int s, b, chunk;
    if (bid < NBLK0)       { s = 0; b = bid / 11; chunk = bid - 11 * b; }
    else if (bid < NBLK01) { int r = bid - NBLK0; s = 1; b = r / 3; chunk = r - 3 * b; }
    else                   { s = 2; b = bid - NBLK01; chunk = 0; }

    const int   W      = (s == 0) ? 52 : ((s == 1) ? 26 : 13);
    const int   A      = W * W;
    const float stride = (s == 0) ? 8.0f : ((s == 1) ? 16.0f : 32.0f);
    const int   soff   = (s == 0) ? 0 : ((s == 1) ? SOFF1 : SOFF2);
    const float* __restrict__ cls = (s == 0) ? cls0 : ((s == 1) ? cls1 : cls2);
    const float* __restrict__ reg = (s == 0) ? reg0 : ((s == 1) ? reg1 : reg2);
    const float* __restrict__ obj = (s == 0) ? obj0 : ((s == 1) ? obj1 : obj2);

    const int tid = threadIdx.x;
    const int a = chunk * 256 + tid;
    const bool active = (a < A);
    const int ay = a / W;
    const int ax = a - ay * W;

    float obj_t = 0.f, cls_t = 0.f, box_t = 0.f, nfg = 0.f;
    if (active) {
        const size_t cidx = (size_t)b * CELLS_PER_IMG + soff + a;
        const int lg = lastGT[cidx];
        const bool fg = (lg >= 0);

        float xo = obj[(size_t)b * A + a];
        obj_t = bce_fast(xo, fg);

        if (fg) {
            nfg = 1.0f;
            unsigned lo = mlo[cidx], hi = mhi[cidx];
            float4 tbv = ((const float4*)bboxes)[(size_t)b * MM + lg];
            float t0 = tbv.x * IMGF, t1 = tbv.y * IMGF, t2 = tbv.z * IMGF, t3 = tbv.w * IMGF;

            // ---- box loss: decode + IoU with target ----
            const float* rp = reg + (size_t)b * 4 * A + a;
            float rx = rp[0], ry = rp[(size_t)A], rw = rp[(size_t)2 * A], rh = rp[(size_t)3 * A];
            float px = ((float)ax + rx) * stride;
            float py = ((float)ay + ry) * stride;
            rw = fminf(fmaxf(rw, -10.0f), 10.0f);
            rh = fminf(fmaxf(rh, -10.0f), 10.0f);
            float pw = __expf(rw) * stride;
            float ph = __expf(rh) * stride;
            float p0 = px - pw * 0.5f, p1 = py - ph * 0.5f;
            float p2 = px + pw * 0.5f, p3 = py + ph * 0.5f;
            float ix1 = fmaxf(p0, t0), iy1 = fmaxf(p1, t1);
            float ix2 = fminf(p2, t2), iy2 = fminf(p3, t3);
            float inter = fmaxf(ix2 - ix1, 0.0f) * fmaxf(iy2 - iy1, 0.0f);
            float pa = (p2 - p0) * (p3 - p1);
            float ta = (t2 - t0) * (t3 - t1);
            float iou = inter / (pa + ta - inter + 1e-7f);
            box_t = 1.0f - iou;

            // ---- cls focal loss over 43 channels (multi-hot target) ----
            const float* cp = cls + (size_t)b * CC * A + a;
            float acc = 0.0f;
            #pragma unroll
            for (int c = 0; c < CC; ++c) {
                float xv = cp[(size_t)c * A];
                bool bit = (c < 32) ? (((lo >> c) & 1u) != 0u) : (((hi >> (c - 32)) & 1u) != 0u);
                acc += focal_fast(xv, bit);
            }
            cls_t = acc;
        }
    }

    // Deterministic block reduction: wave shfl_xor then LDS across 4 waves.
    for (int off = 32; off > 0; off >>= 1) {
        obj_t += __shfl_xor(obj_t, off);
        cls_t += __shfl_xor(cls_t, off);
        box_t += __shfl_xor(box_t, off);
        nfg   += __shfl_xor(nfg,   off);
    }
    __shared__ float s_red[4][4];
    int wid = tid >> 6, lane = tid & 63;
    if (lane == 0) {
        s_red[wid][0] = obj_t; s_red[wid][1] = cls_t;
        s_red[wid][2] = box_t; s_red[wid][3] = nfg;
    }
    __syncthreads();
    if (tid == 0) {
        float o = 0.f, c = 0.f, bx = 0.f, nf = 0.f;
        for (int w = 0; w < 4; ++w) {
            o += s_red[w][0]; c += s_red[w][1]; bx += s_red[w][2]; nf += s_red[w][3];
        }
        float* p = partials + (size_t)bid * 4;
        p[0] = o; p[1] = c; p[2] = bx; p[3] = nf;
    }
}

__global__ __launch_bounds__(256) void v3_final(const float* __restrict__ partials,
                                                float* __restrict__ out)
{
    const int tid = threadIdx.x;
    double o[3] = {0, 0, 0}, c[3] = {0, 0, 0}, bx[3] = {0, 0, 0}, nf[3] = {0, 0, 0};
    for (int i = tid; i < NBLK_TOTAL; i += 256) {
        int s = (i < NBLK0) ? 0 : ((i < NBLK01) ? 1 : 2);
        const float* p = partials + (size_t)i * 4;
        o[s]  += (double)p[0];
        c[s]  += (double)p[1];
        bx[s] += (double)p[2];
        nf[s] += (double)p[3];
    }
    for (int off = 32; off > 0; off >>= 1) {
        for (int s = 0; s < 3; ++s) {
            o[s]  += __shfl_xor(o[s],  off);
            c[s]  += __shfl_xor(c[s],  off);
            bx[s] += __shfl_xor(bx[s], off);
            nf[s] += __shfl_xor(nf[s], off);
        }
    }
    __shared__ double s_red[4][12];
    int wid = tid >> 6, lane = tid & 63;
    if (lane == 0) {
        for (int s = 0; s < 3; ++s) {
            s_red[wid][s * 4 + 0] = o[s];
            s_red[wid][s * 4 + 1] = c[s];
            s_red[wid][s * 4 + 2] = bx[s];
            s_red[wid][s * 4 + 3] = nf[s];
        }
    }
    __syncthreads();
    if (tid == 0) {
        double total = 0.0;
        for (int s = 0; s < 3; ++s) {
            double os = 0, cs = 0, bs = 0, ns = 0;
            for (int w = 0; w < 4; ++w) {
                os += s_red[w][s * 4 + 0];
                cs += s_red[w][s * 4 + 1];
                bs += s_red[w][s * 4 + 2];
                ns += s_red[w][s * 4 + 3];
            }
            double n = (ns > 1.0) ? ns : 1.0;
            total += 0.5 * (cs / (n * (double)CC)) + 7.5 * (bs / n) + 1.0 * (os / n);
        }
        out[0] = (float)(total / 3.0);
    }
}

extern "C" void kernel_launch(void* const* d_in, const int* in_sizes, int n_in,
                              void* d_out, int out_size, void* d_ws, size_t ws_size,
                              hipStream_t stream) {
    const float* cls0 = (const float*)d_in[0];
    const float* reg0 = (const float*)d_in[1];
    const float* obj0 = (const float*)d_in[2];
    const float* cls1 = (const float*)d_in[3];
    const float* reg1 = (const float*)d_in[4];
    const float* obj1 = (const float*)d_in[5];
    const float* cls2 = (const float*)d_in[6];
    const float* reg2 = (const float*)d_in[7];
    const float* obj2 = (const float*)d_in[8];
    const float* bboxes = (const float*)d_in[9];
    const int*   labels = (const int*)d_in[10];

    // workspace layout (all 4B-aligned):
    //   int      lastGT[NCELLS]   1.82 MB
    //   unsigned mlo[NCELLS]      1.82 MB
    //   unsigned mhi[NCELLS]      1.82 MB
    //   float    partials[1920*4] 30 KB
    int*      lastGT   = (int*)d_ws;
    unsigned* mlo      = (unsigned*)(lastGT + NCELLS);
    unsigned* mhi      = mlo + NCELLS;
    float*    partials = (float*)(mhi + NCELLS);

    v3_assign<<<BB, 256, 0, stream>>>(bboxes, labels, lastGT, mlo, mhi);
    v3_main<<<NBLK_TOTAL, 256, 0, stream>>>(cls0, reg0, obj0, cls1, reg1, obj1,
                                            cls2, reg2, obj2, bboxes,
                                            lastGT, mlo, mhi, partials);
    v3_final<<<1, 256, 0, stream>>>(partials, (float*)d_out);
}